// Round 5
// baseline (106.740 us; speedup 1.0000x reference)
//
#include <hip/hip_runtime.h>
#include <math.h>

#define B_IMG 16
#define N_PROP 2048
#define C_CLS 3
#define K_OUT 100
#define NTHREADS 1024
#define NWAVES (NTHREADS / 64)
#define NBLK64 (N_PROP / 64)

__device__ __forceinline__ unsigned long long shfl_xor_u64(unsigned long long v, int lx) {
    unsigned int lo = (unsigned int)__shfl_xor((int)(unsigned int)(v & 0xffffffffull), lx, 64);
    unsigned int hi = (unsigned int)__shfl_xor((int)(unsigned int)(v >> 32), lx, 64);
    return ((unsigned long long)hi << 32) | (unsigned long long)lo;
}
__device__ __forceinline__ float readlane_f(float v, int l) {
    return __int_as_float(__builtin_amdgcn_readlane(__float_as_int(v), l));
}
__device__ __forceinline__ unsigned long long readlane_u64(unsigned long long v, int l) {
    unsigned int lo = (unsigned int)__builtin_amdgcn_readlane((int)(unsigned int)(v & 0xffffffffull), l);
    unsigned int hi = (unsigned int)__builtin_amdgcn_readlane((int)(unsigned int)(v >> 32), l);
    return ((unsigned long long)hi << 32) | (unsigned long long)lo;
}
// Exact replacement for: RN(inter / max(uni,1e-8f)) > 0.5f
// RN(a/b) > 0.5 <=> a/b > 0.5+2^-25 <=> 2a > b*(1+2^-24); b*(1+2^-24) exact in
// double (24+25=49 < 53 bits). Bit-equivalent to the reference decision.
__device__ __forceinline__ bool iou_gt_half(float inter, float uni) {
    double b = (double)fmaxf(uni, 1e-8f);
    return (double)inter * 2.0 > b * 0x1.000001p0;
}

// One workgroup per (image, fg-class). Exact-semantics pipeline:
// softmax -> decode -> clip -> valid mask -> stable sort desc (hybrid reg/LDS
// bitonic) -> greedy NMS (chunk=128, parallel suppression matrix + scalar mask
// resolve, alive-list compaction) -> top-K fill.
__global__ __launch_bounds__(NTHREADS)
void roiheads_kernel(const float* __restrict__ class_logit,
                     const float* __restrict__ box_reg,
                     const float* __restrict__ proposal,
                     const int* __restrict__ image_shape_p,
                     float* __restrict__ out)
{
#pragma clang fp contract(off)
    __shared__ unsigned long long skey[N_PROP];     // 16 KB sort keys
    __shared__ float llo[N_PROP], lhi[N_PROP];      // decoded boxes by original index
    __shared__ float slo[N_PROP], shi[N_PROP];      // boxes in sorted order
    __shared__ unsigned char keep[N_PROP];
    __shared__ unsigned short alv[2][N_PROP];       // alive (undecided) sorted positions
    __shared__ unsigned long long sup0[128], sup1[128]; // chunk suppression matrix halves
    __shared__ float clo[128], chi[128];            // current chunk's kept boxes
    __shared__ unsigned long long kmask[NBLK64];
    __shared__ int wsum[NWAVES];
    __shared__ int sh_nvalid;

    const int tid = threadIdx.x;
    const int lane = tid & 63;
    const int wid = tid >> 6;
    const int img = blockIdx.x >> 1;
    const int cls = blockIdx.x & 1;   // fg class index-1 (actual class = cls+1)

    int raw = image_shape_p[0];
    float imgf = (raw > 0 && raw < 1000000) ? (float)raw : __int_as_float(raw);

    if (tid == 0) sh_nvalid = 0;

    // register-bitonic mapping: thread holds sorted-net positions p0 = 2*tid
    // arranged so wave w owns the contiguous 128-item span [128w, 128w+128).
    const int p0 = (wid << 7) | (lane << 1);
    const int p1 = p0 | 1;

    // ---- step 1: scores + decode -> key straight into registers ----
    auto decode = [&](int n) -> unsigned long long {
#pragma clang fp contract(off)
        const float* lg = class_logit + ((size_t)img * N_PROP + n) * C_CLS;
        float l0 = lg[0], l1 = lg[1], l2 = lg[2];
        float mx = fmaxf(l0, fmaxf(l1, l2));
        float e0 = (float)exp((double)(l0 - mx));
        float e1 = (float)exp((double)(l1 - mx));
        float e2 = (float)exp((double)(l2 - mx));
        float denom = (e0 + e1) + e2;
        float ec = (cls == 0) ? e1 : e2;
        float score = ec / denom;

        const float* dr = box_reg + ((size_t)img * N_PROP + n) * (2 * C_CLS) + 2 * (cls + 1);
        float dx = dr[0];                       // / WX == 1
        float dw = fminf(dr[1], 4.0f);          // / WW == 1, clamp 4
        const float* pp = proposal + ((size_t)img * N_PROP + n) * 2;
        float pA = pp[0], pB = pp[1];
        float w = pB - pA;
        float ctr = pA + 0.5f * w;
        float t = dx * w;
        float pc = t + ctr;
        float pw = (float)exp((double)dw) * w;
        float half = 0.5f * pw;
        float lo = pc - half;
        float hi = pc + half;
        lo = fminf(fmaxf(lo, 0.0f), imgf);
        hi = fminf(fmaxf(hi, 0.0f), imgf);
        bool valid = ((hi - lo) >= 10.0f) && (score >= 0.05f);
        float ms = valid ? score : -1e9f;

        llo[n] = lo; lhi[n] = hi;
        unsigned int u = __float_as_uint(ms);
        unsigned int e = (u & 0x80000000u) ? ~u : (u | 0x80000000u);  // order-preserving map
        return ((unsigned long long)e << 32) |
               (unsigned long long)(0xFFFFFFFFu - (unsigned int)n);   // idx asc on ties
    };
    unsigned long long r0 = decode(p0);
    unsigned long long r1 = decode(p1);

    // ---- step 2: bitonic sort, descending; j<=64 in registers via shfl_xor ----
    auto pass_inreg = [&](int k, int j) {
        if (j == 1) {
            bool desc = ((p0 & k) == 0);
            bool sw = desc ? (r0 < r1) : (r0 > r1);
            if (sw) { unsigned long long t = r0; r0 = r1; r1 = t; }
        } else {
            int lx = j >> 1;
            unsigned long long o0 = shfl_xor_u64(r0, lx);
            unsigned long long o1 = shfl_xor_u64(r1, lx);
            bool desc = ((p0 & k) == 0);     // same for p0/p1 (k>=4 here)
            bool lower = ((p0 & j) == 0);    // same for p0/p1 (j>=2 here)
            bool takeMax = (lower == desc);
            r0 = takeMax ? (r0 > o0 ? r0 : o0) : (r0 < o0 ? r0 : o0);
            r1 = takeMax ? (r1 > o1 ? r1 : o1) : (r1 < o1 ? r1 : o1);
        }
    };

    for (int k = 2; k <= 128; k <<= 1)
        for (int j = k >> 1; j >= 1; j >>= 1)
            pass_inreg(k, j);

    for (int k = 256; k <= N_PROP; k <<= 1) {
        skey[p0] = r0; skey[p1] = r1;
        __syncthreads();
        for (int j = k >> 1; j >= 128; j >>= 1) {
            int i = ((tid & ~(j - 1)) << 1) | (tid & (j - 1));
            int part = i | j;
            unsigned long long a = skey[i], b = skey[part];
            bool desc_blk = ((i & k) == 0);
            bool sw = desc_blk ? (a < b) : (a > b);
            if (sw) { skey[i] = b; skey[part] = a; }
            __syncthreads();
        }
        r0 = skey[p0]; r1 = skey[p1];
        for (int j = 64; j >= 1; j >>= 1)
            pass_inreg(k, j);
    }
    skey[p0] = r0; skey[p1] = r1;
    __syncthreads();

    // ---- step 3: gather sorted boxes, count valid, init keep=0 + alive list ----
    for (int i = tid; i < N_PROP; i += NTHREADS) {
        unsigned long long kk = skey[i];
        unsigned int e = (unsigned int)(kk >> 32);
        unsigned int sb = (e & 0x80000000u) ? (e & 0x7FFFFFFFu) : ~e;
        float s = __uint_as_float(sb);
        unsigned int n = 0xFFFFFFFFu - (unsigned int)(kk & 0xFFFFFFFFull);
        slo[i] = llo[n];
        shi[i] = lhi[n];
        keep[i] = 0;
        bool v = (s > -5e8f);    // keep0 = s > 0.5*NEG  (valid items sort first)
        unsigned long long mb = __ballot(v);
        if (lane == 0) atomicAdd(&sh_nvalid, __popcll(mb));
        alv[0][i] = (unsigned short)i;   // valid items are positions [0, n_valid)
    }
    __syncthreads();

    int na = sh_nvalid;
    int cur = 0;
    const unsigned long long below = (1ull << lane) - 1ull;

    // ---- step 4: greedy NMS over compacted alive list, chunk=128 ----
    while (na > 0) {
        const int m = (na < 128) ? na : 128;

        // 4a: build 128x128 suppression matrix in parallel (16 row-half units/wave)
        for (int i = 0; i < 16; ++i) {
            int u = (wid << 4) | i;
            int rr = u >> 1, h = u & 1;
            unsigned long long mb = 0;
            if (!(h == 0 && rr >= 64)) {          // rows >=64 never kill cols <64
                unsigned short pr = alv[cur][rr];
                float rlo = slo[pr], rhi = shi[pr];   // broadcast reads
                int jc = (h << 6) | lane;
                unsigned short pq = alv[cur][jc];
                float qlo = slo[pq], qhi = shi[pq];
                float inter = fmaxf(fminf(rhi, qhi) - fmaxf(rlo, qlo), 0.0f);
                float uni = ((rhi - rlo) + (qhi - qlo)) - inter;
                bool kill = (jc > rr) && iou_gt_half(inter, uni);
                mb = __ballot(kill);
            }
            if (lane == 0) { if (h == 0) sup0[rr] = mb; else sup1[rr] = mb; }
        }
        __syncthreads();

        // 4b: scalar greedy mask resolve (redundant in every wave; rows in regs)
        unsigned long long rw00 = sup0[lane];        // row=lane,   cols 0-63
        unsigned long long rw01 = sup1[lane];        // row=lane,   cols 64-127
        unsigned long long rw11 = sup1[64 + lane];   // row=64+lane, cols 64-127
        unsigned long long A0 = (m >= 64) ? ~0ull : ((1ull << m) - 1ull);
        unsigned long long A1 = (m > 64) ? ((m >= 128) ? ~0ull : ((1ull << (m - 64)) - 1ull)) : 0ull;
        unsigned long long k0 = 0, k1 = 0;
        while (A0) {
            int c = __builtin_ctzll(A0);
            k0 |= (1ull << c);
            A0 &= ~(readlane_u64(rw00, c) | (1ull << c));
            A1 &= ~readlane_u64(rw01, c);
        }
        while (A1) {
            int c = __builtin_ctzll(A1);
            k1 |= (1ull << c);
            A1 &= ~(readlane_u64(rw11, c) | (1ull << c));
        }
        const int cnt0 = __popcll(k0);
        const int cnt = cnt0 + __popcll(k1);

        // 4c: mark kept + build compact kept-box list (threads 0..127)
        if (tid < 128) {
            unsigned long long km = (tid < 64) ? k0 : k1;
            bool alive = (tid < m) && ((km >> lane) & 1ull);
            if (alive) {
                unsigned short p = alv[cur][tid];
                keep[p] = 1;
                int rank = __popcll(km & below) + ((tid < 64) ? 0 : cnt0);
                clo[rank] = slo[p]; chi[rank] = shi[p];
            }
        }
        __syncthreads();

        // 4d: sweep remaining alive items vs kept boxes (registers + readlane);
        // compact survivors with redundant all-thread prefix.
        float klo0 = 0.0f, khi0 = 0.0f, klo1 = 0.0f, khi1 = 0.0f;
        if (lane < cnt) { klo0 = clo[lane]; khi0 = chi[lane]; }
        if (64 + lane < cnt) { klo1 = clo[64 + lane]; khi1 = chi[64 + lane]; }
        const int c1 = (cnt < 64) ? cnt : 64;
        int base = 0;
        for (int start = m; start < na; start += NTHREADS) {
            int t = start + tid;
            unsigned short q = 0;
            bool surv = false;
            if (t < na) {
                q = alv[cur][t];
                float qlo = slo[q], qhi = shi[q];
                float qw = qhi - qlo;
                bool dead = false;
                for (int r = 0; r < c1; ++r) {
                    float cl = readlane_f(klo0, r);
                    float ch = readlane_f(khi0, r);
                    float inter = fmaxf(fminf(qhi, ch) - fmaxf(qlo, cl), 0.0f);
                    float uni = (qw + (ch - cl)) - inter;
                    dead |= iou_gt_half(inter, uni);
                }
                for (int r = 64; r < cnt; ++r) {
                    float cl = readlane_f(klo1, r - 64);
                    float ch = readlane_f(khi1, r - 64);
                    float inter = fmaxf(fminf(qhi, ch) - fmaxf(qlo, cl), 0.0f);
                    float uni = (qw + (ch - cl)) - inter;
                    dead |= iou_gt_half(inter, uni);
                }
                surv = !dead;
            }
            unsigned long long mb = __ballot(surv);
            if (lane == 0) wsum[wid] = __popcll(mb);
            __syncthreads();
            int off = base, tot = base;
            for (int w2 = 0; w2 < NWAVES; ++w2) {
                int c2 = wsum[w2];
                if (w2 < wid) off += c2;
                tot += c2;
            }
            if (surv) alv[cur ^ 1][off + __popcll(mb & below)] = q;
            base = tot;
            __syncthreads();
        }
        na = base;
        cur ^= 1;
    }

    // ---- step 5: top-K fill (reproduces lax.top_k tie-breaking exactly) ----
    // pass 1: build per-64-block keep masks in parallel
    for (int blk = wid; blk < NBLK64; blk += NWAVES) {
        bool kk = keep[blk * 64 + lane] != 0;
        unsigned long long mb = __ballot(kk);
        if (lane == 0) kmask[blk] = mb;
    }
    __syncthreads();
    // pass 2: each wave emits its blocks using prefix counts from kmask
    {
        float* outp = out + (((size_t)img * 2 + cls) * K_OUT) * 3;
        for (int blk = wid; blk < NBLK64; blk += NWAVES) {
            int kc = 0, nc = 0, nk = 0;
            for (int b = 0; b < NBLK64; ++b) {
                int pc = __popcll(kmask[b]);
                nk += pc;
                if (b < blk) { kc += pc; nc += 64 - pc; }
            }
            if (kc >= K_OUT && nk + nc >= K_OUT && nc >= K_OUT) continue; // nothing left to emit
            int p = blk * 64 + lane;
            unsigned long long mb = kmask[blk];
            bool k = (mb >> lane) & 1ull;
            int rk = kc + __popcll(mb & below);
            int rn = nc + __popcll((~mb) & below);
            if (k) {
                if (rk < K_OUT) {
                    unsigned long long kk2 = skey[p];
                    unsigned int e = (unsigned int)(kk2 >> 32);
                    unsigned int sb = (e & 0x80000000u) ? (e & 0x7FFFFFFFu) : ~e;
                    outp[rk * 3 + 0] = slo[p];
                    outp[rk * 3 + 1] = shi[p];
                    outp[rk * 3 + 2] = __uint_as_float(sb);
                }
            } else {
                int oi = nk + rn;
                if (oi < K_OUT) {
                    outp[oi * 3 + 0] = slo[p];
                    outp[oi * 3 + 1] = shi[p];
                    outp[oi * 3 + 2] = -1e9f;
                }
            }
        }
    }
}

extern "C" void kernel_launch(void* const* d_in, const int* in_sizes, int n_in,
                              void* d_out, int out_size, void* d_ws, size_t ws_size,
                              hipStream_t stream) {
    const float* class_logit = (const float*)d_in[0];
    const float* box_reg     = (const float*)d_in[1];
    const float* prop        = (const float*)d_in[2];
    const int*   image_shape = (const int*)d_in[3];
    float* out = (float*)d_out;

    roiheads_kernel<<<dim3(B_IMG * 2), dim3(NTHREADS), 0, stream>>>(
        class_logit, box_reg, prop, image_shape, out);
}

// Round 6
// 97.979 us; speedup vs baseline: 1.0894x; 1.0894x over previous
//
#include <hip/hip_runtime.h>
#include <math.h>

#define B_IMG 16
#define N_PROP 2048
#define C_CLS 3
#define K_OUT 100
#define NTHREADS 1024
#define NWAVES (NTHREADS / 64)
#define NBLK64 (N_PROP / 64)

__device__ __forceinline__ unsigned long long shfl_xor_u64(unsigned long long v, int lx) {
    unsigned int lo = (unsigned int)__shfl_xor((int)(unsigned int)(v & 0xffffffffull), lx, 64);
    unsigned int hi = (unsigned int)__shfl_xor((int)(unsigned int)(v >> 32), lx, 64);
    return ((unsigned long long)hi << 32) | (unsigned long long)lo;
}
__device__ __forceinline__ float readlane_f(float v, int l) {
    return __int_as_float(__builtin_amdgcn_readlane(__float_as_int(v), l));
}
// Exact replacement for: RN(inter / max(uni,1e-8f)) > 0.5f
// RN(a/b) > 0.5 <=> a/b > 0.5+2^-25 <=> 2a > b*(1+2^-24); b*(1+2^-24) exact in
// double (24+25=49 < 53 bits). Bit-equivalent to the reference decision.
__device__ __forceinline__ bool iou_gt_half(float inter, float uni) {
    double b = (double)fmaxf(uni, 1e-8f);
    return (double)inter * 2.0 > b * 0x1.000001p0;
}

// One workgroup per (image, fg-class). Exact-semantics pipeline:
// softmax -> decode -> clip -> valid mask -> stable sort desc (hybrid reg/LDS
// bitonic) -> greedy NMS (alive-list compaction, EARLY EXIT once kept >= K:
// later keep decisions are provably unused by the K-slot output) -> top-K fill.
__global__ __launch_bounds__(NTHREADS)
void roiheads_kernel(const float* __restrict__ class_logit,
                     const float* __restrict__ box_reg,
                     const float* __restrict__ proposal,
                     const int* __restrict__ image_shape_p,
                     float* __restrict__ out)
{
#pragma clang fp contract(off)
    __shared__ unsigned long long skey[N_PROP];     // 16 KB sort keys
    __shared__ float llo[N_PROP], lhi[N_PROP];      // decoded boxes by original index
    __shared__ float slo[N_PROP], shi[N_PROP];      // boxes in sorted order
    __shared__ unsigned char keep[N_PROP];
    __shared__ unsigned short alv[2][N_PROP];       // alive (undecided) sorted positions
    __shared__ float clo[64], chi[64];              // current chunk's kept boxes
    __shared__ unsigned long long kmask[NBLK64];
    __shared__ int wsum[NWAVES];
    __shared__ int sh_nvalid, sh_ccnt;

    const int tid = threadIdx.x;
    const int lane = tid & 63;
    const int wid = tid >> 6;
    const int img = blockIdx.x >> 1;
    const int cls = blockIdx.x & 1;   // fg class index-1 (actual class = cls+1)

    int raw = image_shape_p[0];
    float imgf = (raw > 0 && raw < 1000000) ? (float)raw : __int_as_float(raw);

    if (tid == 0) sh_nvalid = 0;

    // register-bitonic mapping: thread holds sorted-net positions p0 = 2*tid
    // arranged so wave w owns the contiguous 128-item span [128w, 128w+128).
    const int p0 = (wid << 7) | (lane << 1);
    const int p1 = p0 | 1;

    // ---- step 1: scores + decode -> key straight into registers ----
    auto decode = [&](int n) -> unsigned long long {
#pragma clang fp contract(off)
        const float* lg = class_logit + ((size_t)img * N_PROP + n) * C_CLS;
        float l0 = lg[0], l1 = lg[1], l2 = lg[2];
        float mx = fmaxf(l0, fmaxf(l1, l2));
        float e0 = (float)exp((double)(l0 - mx));
        float e1 = (float)exp((double)(l1 - mx));
        float e2 = (float)exp((double)(l2 - mx));
        float denom = (e0 + e1) + e2;
        float ec = (cls == 0) ? e1 : e2;
        float score = ec / denom;

        const float* dr = box_reg + ((size_t)img * N_PROP + n) * (2 * C_CLS) + 2 * (cls + 1);
        float dx = dr[0];                       // / WX == 1
        float dw = fminf(dr[1], 4.0f);          // / WW == 1, clamp 4
        const float* pp = proposal + ((size_t)img * N_PROP + n) * 2;
        float pA = pp[0], pB = pp[1];
        float w = pB - pA;
        float ctr = pA + 0.5f * w;
        float t = dx * w;
        float pc = t + ctr;
        float pw = (float)exp((double)dw) * w;
        float half = 0.5f * pw;
        float lo = pc - half;
        float hi = pc + half;
        lo = fminf(fmaxf(lo, 0.0f), imgf);
        hi = fminf(fmaxf(hi, 0.0f), imgf);
        bool valid = ((hi - lo) >= 10.0f) && (score >= 0.05f);
        float ms = valid ? score : -1e9f;

        llo[n] = lo; lhi[n] = hi;
        unsigned int u = __float_as_uint(ms);
        unsigned int e = (u & 0x80000000u) ? ~u : (u | 0x80000000u);  // order-preserving map
        return ((unsigned long long)e << 32) |
               (unsigned long long)(0xFFFFFFFFu - (unsigned int)n);   // idx asc on ties
    };
    unsigned long long r0 = decode(p0);
    unsigned long long r1 = decode(p1);

    // ---- step 2: bitonic sort, descending; j<=64 in registers via shfl_xor ----
    auto pass_inreg = [&](int k, int j) {
        if (j == 1) {
            bool desc = ((p0 & k) == 0);
            bool sw = desc ? (r0 < r1) : (r0 > r1);
            if (sw) { unsigned long long t = r0; r0 = r1; r1 = t; }
        } else {
            int lx = j >> 1;
            unsigned long long o0 = shfl_xor_u64(r0, lx);
            unsigned long long o1 = shfl_xor_u64(r1, lx);
            bool desc = ((p0 & k) == 0);     // same for p0/p1 (k>=4 here)
            bool lower = ((p0 & j) == 0);    // same for p0/p1 (j>=2 here)
            bool takeMax = (lower == desc);
            r0 = takeMax ? (r0 > o0 ? r0 : o0) : (r0 < o0 ? r0 : o0);
            r1 = takeMax ? (r1 > o1 ? r1 : o1) : (r1 < o1 ? r1 : o1);
        }
    };

    for (int k = 2; k <= 128; k <<= 1)
        for (int j = k >> 1; j >= 1; j >>= 1)
            pass_inreg(k, j);

    for (int k = 256; k <= N_PROP; k <<= 1) {
        skey[p0] = r0; skey[p1] = r1;
        __syncthreads();
        for (int j = k >> 1; j >= 128; j >>= 1) {
            int i = ((tid & ~(j - 1)) << 1) | (tid & (j - 1));
            int part = i | j;
            unsigned long long a = skey[i], b = skey[part];
            bool desc_blk = ((i & k) == 0);
            bool sw = desc_blk ? (a < b) : (a > b);
            if (sw) { skey[i] = b; skey[part] = a; }
            __syncthreads();
        }
        r0 = skey[p0]; r1 = skey[p1];
        for (int j = 64; j >= 1; j >>= 1)
            pass_inreg(k, j);
    }
    skey[p0] = r0; skey[p1] = r1;
    __syncthreads();

    // ---- step 3: gather sorted boxes, count valid, init keep=0 + alive list ----
    for (int i = tid; i < N_PROP; i += NTHREADS) {
        unsigned long long kk = skey[i];
        unsigned int e = (unsigned int)(kk >> 32);
        unsigned int sb = (e & 0x80000000u) ? (e & 0x7FFFFFFFu) : ~e;
        float s = __uint_as_float(sb);
        unsigned int n = 0xFFFFFFFFu - (unsigned int)(kk & 0xFFFFFFFFull);
        slo[i] = llo[n];
        shi[i] = lhi[n];
        keep[i] = 0;
        bool v = (s > -5e8f);    // keep0 = s > 0.5*NEG  (valid items sort first)
        unsigned long long mb = __ballot(v);
        if (lane == 0) atomicAdd(&sh_nvalid, __popcll(mb));
        alv[0][i] = (unsigned short)i;   // valid items are positions [0, n_valid)
    }
    __syncthreads();

    int na = sh_nvalid;
    int cur = 0;
    int tk = 0;      // cumulative kept; once >= K_OUT, later decisions are unused
    const unsigned long long below = (1ull << lane) - 1ull;

    // ---- step 4: greedy NMS over compacted alive list, early-exit at K kept ----
    while (na > 0) {
        const int m = (na < 64) ? na : 64;
        if (tid < 64) {
            bool inr = (lane < m);
            unsigned short p = inr ? alv[cur][lane] : (unsigned short)0;
            float blo = inr ? slo[p] : 0.0f;
            float bhi = inr ? shi[p] : 0.0f;
            float bw = bhi - blo;
            unsigned long long A = (m >= 64) ? ~0ull : ((1ull << m) - 1ull);
            unsigned long long kept = 0;
            while (A) {
                int c = __builtin_ctzll(A);
                float cl = readlane_f(blo, c);
                float ch = readlane_f(bhi, c);
                float inter = fmaxf(fminf(bhi, ch) - fmaxf(blo, cl), 0.0f);
                float uni = bw + (ch - cl) - inter;
                bool kill = (lane > c) && iou_gt_half(inter, uni);
                unsigned long long row = __ballot(kill);
                kept |= (1ull << c);
                A &= ~(row | (1ull << c));
            }
            bool alive = inr && ((kept >> lane) & 1ull);
            if (alive) keep[p] = 1;
            int rank = __popcll(kept & below);
            if (alive) { clo[rank] = blo; chi[rank] = bhi; }
            if (lane == 0) sh_ccnt = __popcll(kept);
        }
        __syncthreads();
        const int cnt = sh_ccnt;
        tk += cnt;
        if (tk >= K_OUT) break;   // ranks >= K never emitted; fillers impossible (nk >= K)

        // sweep remaining alive items vs chunk's kept boxes (held in registers);
        // compact survivors with redundant all-thread prefix (2 barriers/stride).
        float klo = 0.0f, khi = 0.0f;
        if (lane < cnt) { klo = clo[lane]; khi = chi[lane]; }
        int base = 0;
        for (int start = 64; start < na; start += NTHREADS) {
            int t = start + tid;
            unsigned short q = 0;
            bool surv = false;
            if (t < na) {
                q = alv[cur][t];
                float qlo = slo[q], qhi = shi[q];
                float qw = qhi - qlo;
                bool dead = false;
                for (int r = 0; r < cnt; ++r) {
                    float cl = readlane_f(klo, r);
                    float ch = readlane_f(khi, r);
                    float inter = fmaxf(fminf(qhi, ch) - fmaxf(qlo, cl), 0.0f);
                    float uni = qw + (ch - cl) - inter;
                    dead |= iou_gt_half(inter, uni);
                }
                surv = !dead;
            }
            unsigned long long mb = __ballot(surv);
            if (lane == 0) wsum[wid] = __popcll(mb);
            __syncthreads();
            int off = base, tot = base;
            for (int w2 = 0; w2 < NWAVES; ++w2) {
                int c2 = wsum[w2];
                if (w2 < wid) off += c2;
                tot += c2;
            }
            if (surv) alv[cur ^ 1][off + __popcll(mb & below)] = q;
            base = tot;
            __syncthreads();
        }
        na = base;
        cur ^= 1;
    }

    // ---- step 5: top-K fill (reproduces lax.top_k tie-breaking exactly) ----
    // pass 1: build per-64-block keep masks in parallel
    for (int blk = wid; blk < NBLK64; blk += NWAVES) {
        bool kk = keep[blk * 64 + lane] != 0;
        unsigned long long mb = __ballot(kk);
        if (lane == 0) kmask[blk] = mb;
    }
    __syncthreads();
    // pass 2: each wave emits its blocks using prefix counts from kmask
    {
        float* outp = out + (((size_t)img * 2 + cls) * K_OUT) * 3;
        for (int blk = wid; blk < NBLK64; blk += NWAVES) {
            int kc = 0, nc = 0, nk = 0;
            for (int b = 0; b < NBLK64; ++b) {
                int pc = __popcll(kmask[b]);
                nk += pc;
                if (b < blk) { kc += pc; nc += 64 - pc; }
            }
            if (kc >= K_OUT && nk + nc >= K_OUT && nc >= K_OUT) continue; // nothing left to emit
            int p = blk * 64 + lane;
            unsigned long long mb = kmask[blk];
            bool k = (mb >> lane) & 1ull;
            int rk = kc + __popcll(mb & below);
            int rn = nc + __popcll((~mb) & below);
            if (k) {
                if (rk < K_OUT) {
                    unsigned long long kk2 = skey[p];
                    unsigned int e = (unsigned int)(kk2 >> 32);
                    unsigned int sb = (e & 0x80000000u) ? (e & 0x7FFFFFFFu) : ~e;
                    outp[rk * 3 + 0] = slo[p];
                    outp[rk * 3 + 1] = shi[p];
                    outp[rk * 3 + 2] = __uint_as_float(sb);
                }
            } else {
                int oi = nk + rn;
                if (oi < K_OUT) {
                    outp[oi * 3 + 0] = slo[p];
                    outp[oi * 3 + 1] = shi[p];
                    outp[oi * 3 + 2] = -1e9f;
                }
            }
        }
    }
}

extern "C" void kernel_launch(void* const* d_in, const int* in_sizes, int n_in,
                              void* d_out, int out_size, void* d_ws, size_t ws_size,
                              hipStream_t stream) {
    const float* class_logit = (const float*)d_in[0];
    const float* box_reg     = (const float*)d_in[1];
    const float* prop        = (const float*)d_in[2];
    const int*   image_shape = (const int*)d_in[3];
    float* out = (float*)d_out;

    roiheads_kernel<<<dim3(B_IMG * 2), dim3(NTHREADS), 0, stream>>>(
        class_logit, box_reg, prop, image_shape, out);
}